// Round 7
// baseline (97.549 us; speedup 1.0000x reference)
//
#include <hip/hip_runtime.h>

// OPU via MFMA. R22 = SINGLE fused kernel: hi/lo split done on the fly through LDS,
// no workspace, no presplit kernel, no second launch.
// R21 post-mortem (87.9 ~= R17 85.9): interior micro-opts (depth-3 prefetch, pk quant)
// neutral; per-rep budget = fill ~45 (harness ws poison, in-window per R20 arithmetic)
// + presplit ~12 + main ~24 + gaps. Only remaining big lever: presplit + its launch
// boundary + the 24MB ws round-trip.
// R22 design: per 2-chunk step each block stages raw A 64x32 + B 32x64 f32, converts
// via the same packed split tables (bit-identical split_pack; j = k mod 16 compile-time
// per slot), writes the EXACT same 4KB page layout ([hl][rg|ng][oct][32][k8]) into a
// 2x16KB double-buffered LDS image; the proven fragment-read + 3-MFMA + biased-quant
// path consumes it unchanged. Raw bytes/lane/chunk = 64B = same as split u16 reads ->
// HBM/L2 traffic unchanged. Pipeline/step: LD(next) -> COMPUTE(cur) -> CONV(next) ->
// one barrier (stage and compute touch different buffers; single barrier covers both
// hazards). Wave = output quadrant (rg,ng) over full K; direct store uses the
// R18-verified C/D mapping (absmax-16-passing). Conversion redundancy (A x16, B x32)
// ~4-5us VALU/SIMD, hidden in the stall bubbles that kept MfmaUtil ~25%.
// Carried: biased-magic quant (res at 1.5*2^23; fp32 RNE in res+=acc IS the per-chunk
// ADC rint; swing <=1120 << 4.19M), AlBl dropped (|err|<=4e-6), clip provably dead,
// per-XCD swizzle. R16 lesson: no hipLaunchCooperativeKernel under graph capture.

typedef unsigned int u32;
typedef unsigned short u16;
typedef _Float16 f16x8 __attribute__((ext_vector_type(8)));
typedef float f32x16 __attribute__((ext_vector_type(16)));

#define N_TOT 1024
#define K_TOT 1024
#define RBIAS 12582912.0f  // 1.5 * 2^23: fp32 ulp = 1.0, integer-grid RNE in the add

__device__ __forceinline__ u32 split_pack(float a) {
  _Float16 h = (_Float16)a;              // v_cvt_f16_f32 (RNE)
  _Float16 l = (_Float16)(a - (float)h); // exact fp32 sub then RNE
  return (u32)__builtin_bit_cast(u16, h) | ((u32)__builtin_bit_cast(u16, l) << 16);
}
__device__ __forceinline__ u32 pk_lo(u32 a, u32 b) { return (a & 0xffffu) | (b << 16); }
__device__ __forceinline__ u32 pk_hi(u32 a, u32 b) { return (a >> 16) | (b & 0xffff0000u); }

__global__ __launch_bounds__(256, 2) void opu_fused(
    const float* __restrict__ x, const float* __restrict__ w,
    const float* __restrict__ vl, const float* __restrict__ wl,
    float* __restrict__ out)
{
  __shared__ u32 tabX[256];
  __shared__ u32 tabW[256];
  // [buf][A=0/B=4096][chunk:2048][hl:1024][rg|ng:512][oct:256][row|n32:8][k8] u16
  __shared__ __align__(16) u16 stg[2 * 8192];

  const int tid  = threadIdx.x;
  const int wave = tid >> 6;
  const int lane = tid & 63;
  const int oct  = lane >> 5;
  const int ll   = lane & 31;
  const int rg   = wave >> 1;     // owned A row-group (32 rows)
  const int ng   = wave & 1;      // owned B col-group (32 cols)

  const int bx   = blockIdx.x;
  const int nblk = (bx & 1) + 2 * ((bx >> 3) & 7);   // 0..15  per-XCD swizzle
  const int mblk = ((bx >> 1) & 3) + 4 * (bx >> 6);  // 0..31

  // ---- staging roles ----
  // A: thread = (r = tid>>2, q = tid&3); loads x[mblk*64+r][kg*32 + q*8 .. +8)
  // B: thread = (n = tid&63, kb = tid>>6); loads w[kg*32 + kb*8 + e][nblk*64+n]
  const float* pxA = x + (size_t)(mblk * 64 + (tid >> 2)) * K_TOT + (tid & 3) * 8;
  const float* pxB = w + (size_t)((tid >> 6) * 8) * N_TOT + nblk * 64 + (tid & 63);

  // split-table row bases (u32 idx): j*16, j = (q&1)*8+e (A) / (kb&1)*8+e (B)
  const int tbA = (tid & 1) * 128;
  const int tbB = ((tid >> 6) & 1) * 128;

  // LDS write offsets (u16 units) for this thread's hi uint4; lo at +1024
  const int offA = ((tid & 3) >> 1) * 2048 + (tid >> 7) * 512 + (tid & 1) * 256
                 + ((tid >> 2) & 31) * 8;
  const int offB = 4096 + (tid >> 7) * 2048 + ((tid >> 5) & 1) * 512
                 + ((tid >> 6) & 1) * 256 + (tid & 31) * 8;

  // LDS read offsets (u16 units) for this wave's fragments
  const int cofA = rg * 512 + lane * 8;          // + c*2048 (+1024 for lo)
  const int cofB = 4096 + ng * 512 + lane * 8;

  u16* sbase = &stg[0];

  float va[8], vb[8];

#define LD(kg)                                                        \
  do {                                                                \
    const float4 _a0 = *(const float4*)(pxA + (size_t)(kg) * 32);     \
    const float4 _a1 = *(const float4*)(pxA + (size_t)(kg) * 32 + 4); \
    va[0] = _a0.x; va[1] = _a0.y; va[2] = _a0.z; va[3] = _a0.w;       \
    va[4] = _a1.x; va[5] = _a1.y; va[6] = _a1.z; va[7] = _a1.w;       \
    vb[0] = pxB[(size_t)((kg) * 32 + 0) * N_TOT];                     \
    vb[1] = pxB[(size_t)((kg) * 32 + 1) * N_TOT];                     \
    vb[2] = pxB[(size_t)((kg) * 32 + 2) * N_TOT];                     \
    vb[3] = pxB[(size_t)((kg) * 32 + 3) * N_TOT];                     \
    vb[4] = pxB[(size_t)((kg) * 32 + 4) * N_TOT];                     \
    vb[5] = pxB[(size_t)((kg) * 32 + 5) * N_TOT];                     \
    vb[6] = pxB[(size_t)((kg) * 32 + 6) * N_TOT];                     \
    vb[7] = pxB[(size_t)((kg) * 32 + 7) * N_TOT];                     \
  } while (0)

#define CONV(BUF)                                                            \
  do {                                                                       \
    u32 hp[4], lp[4];                                                        \
    _Pragma("unroll")                                                        \
    for (int e2 = 0; e2 < 4; ++e2) {                                         \
      const u32 t0 = tabX[tbA + (2 * e2) * 16 + (int)(va[2 * e2] + 8.0f)];   \
      const u32 t1 = tabX[tbA + (2 * e2 + 1) * 16 + (int)(va[2 * e2 + 1] + 8.0f)]; \
      hp[e2] = pk_lo(t0, t1); lp[e2] = pk_hi(t0, t1);                        \
    }                                                                        \
    *(uint4*)(sbase + (BUF) * 8192 + offA)        = make_uint4(hp[0], hp[1], hp[2], hp[3]); \
    *(uint4*)(sbase + (BUF) * 8192 + offA + 1024) = make_uint4(lp[0], lp[1], lp[2], lp[3]); \
    _Pragma("unroll")                                                        \
    for (int e2 = 0; e2 < 4; ++e2) {                                         \
      const u32 t0 = tabW[tbB + (2 * e2) * 16 + (int)(vb[2 * e2] + 8.0f)];   \
      const u32 t1 = tabW[tbB + (2 * e2 + 1) * 16 + (int)(vb[2 * e2 + 1] + 8.0f)]; \
      hp[e2] = pk_lo(t0, t1); lp[e2] = pk_hi(t0, t1);                        \
    }                                                                        \
    *(uint4*)(sbase + (BUF) * 8192 + offB)        = make_uint4(hp[0], hp[1], hp[2], hp[3]); \
    *(uint4*)(sbase + (BUF) * 8192 + offB + 1024) = make_uint4(lp[0], lp[1], lp[2], lp[3]); \
  } while (0)

  float res[16];
#pragma unroll
  for (int i = 0; i < 16; ++i) res[i] = RBIAS;  // biased: each add RNE-rounds to int grid
  const f32x16 fzero = {};

#define COMPUTE(BUF)                                                              \
  do {                                                                            \
    const u16* ra = sbase + (BUF) * 8192 + cofA;                                  \
    const u16* rb = sbase + (BUF) * 8192 + cofB;                                  \
    _Pragma("unroll")                                                             \
    for (int c = 0; c < 2; ++c) {                                                 \
      const uint4 uAH = *(const uint4*)(ra + c * 2048);                           \
      const uint4 uAL = *(const uint4*)(ra + c * 2048 + 1024);                    \
      const uint4 uBH = *(const uint4*)(rb + c * 2048);                           \
      const uint4 uBL = *(const uint4*)(rb + c * 2048 + 1024);                    \
      const f16x8 AH = __builtin_bit_cast(f16x8, uAH);                            \
      const f16x8 AL = __builtin_bit_cast(f16x8, uAL);                            \
      const f16x8 BH = __builtin_bit_cast(f16x8, uBH);                            \
      const f16x8 BL = __builtin_bit_cast(f16x8, uBL);                            \
      f32x16 a = __builtin_amdgcn_mfma_f32_32x32x16_f16(AH, BH, fzero, 0, 0, 0);  \
      a = __builtin_amdgcn_mfma_f32_32x32x16_f16(AL, BH, a, 0, 0, 0);             \
      a = __builtin_amdgcn_mfma_f32_32x32x16_f16(AH, BL, a, 0, 0, 0);             \
      _Pragma("unroll")                                                           \
      for (int i = 0; i < 16; ++i) res[i] += a[i];                                \
    }                                                                             \
  } while (0)

  // ---- prologue: tables + first slice ----
  LD(0);
  {
    const int j = tid >> 4, xi = tid & 15;
    const float base = (float)(xi - 8);
    tabX[tid] = split_pack(base + vl[j * 16 + xi]);
    tabW[tid] = split_pack((base + wl[j * 16 + xi]) * 0.0625f);
  }
  __syncthreads();   // tables ready (first loads still in flight)
  CONV(0);
  __syncthreads();   // buf0 ready

  // ---- main: 32 steps of 2 chunks, double-buffered, 1 barrier/step ----
#pragma unroll 1
  for (int kg2 = 0; kg2 < 16; ++kg2) {
    LD(2 * kg2 + 1);
    COMPUTE(0);
    CONV(1);
    __syncthreads();
    if (kg2 < 15) LD(2 * kg2 + 2);
    COMPUTE(1);
    if (kg2 < 15) CONV(0);
    __syncthreads();
  }

  // ---- direct per-wave store (R18-verified 32x32 C/D mapping) ----
  float* op = out + (size_t)(mblk * 64 + rg * 32 + 4 * oct) * N_TOT
                  + nblk * 64 + ng * 32 + ll;
#pragma unroll
  for (int i = 0; i < 16; ++i) {
    const int r = (i & 3) + 8 * (i >> 2);
    op[(size_t)r * N_TOT] = (res[i] - RBIAS) * 16.0f;
  }
}

extern "C" void kernel_launch(void* const* d_in, const int* in_sizes, int n_in,
                              void* d_out, int out_size, void* d_ws, size_t ws_size,
                              hipStream_t stream)
{
  const float* input  = (const float*)d_in[0];
  const float* weight = (const float*)d_in[1];
  const float* vmap   = (const float*)d_in[2];
  const float* wmap   = (const float*)d_in[3];
  float* out = (float*)d_out;
  (void)d_ws; (void)ws_size;   // workspace unused: split is fused through LDS

  opu_fused<<<512, 256, 0, stream>>>(input, weight, vmap, wmap, out);
}